// Round 12
// baseline (184.766 us; speedup 1.0000x reference)
//
#include <hip/hip_runtime.h>

// QKBmm: out[b,m,q,kv] = sum_h q[b,m,q,h] * k[b,m,kv,h]
// B=2, M=16, QT=1024, KVT=4096, H=128. fp32 in/out, bf16 MFMA compute.
// Write-bound: 512 MB out; inputs L3-resident. Floor ~91us @6.7TB/s.
// R6 WIN (4 blk/CU). R8 121.9 (5 blk/CU). R9 FAILED (manual pipeline).
// R10 FAILED (200us): plain write-back stores thrash L2 (input eviction).
// R11 WIN 118.7: 32x32x16 MFMA -> every scalar NT store = 2 full 128B lines.
// R12: A/B store cache flags — `sc1` (bypass L2, ALLOCATE in memory-side L3)
//     instead of `nt` (no-allocate everywhere). Theory: dispatch end needs
//     visibility not durability; dirty-in-L3 defers up to 256MB of DRAM
//     writeback past kernel end (the fill kernel's 6.7TB/s path), while L2
//     bypass keeps q/k resident (R10's failure mode avoided).

#define QT   1024
#define KVT  4096
#define HD   128
#define NXCD 8

using bf16x8 = __attribute__((ext_vector_type(8))) __bf16;
using bf16x4 = __attribute__((ext_vector_type(4))) __bf16;
using f32x16 = __attribute__((ext_vector_type(16))) float;

__device__ __forceinline__ void store_sc1(float* p, float v) {
    // Bypass L2 (sc1) but no NT hint -> normal allocation in memory-side L3.
    asm volatile("global_store_dword %0, %1, off sc1"
                 :: "v"(p), "v"(v) : "memory");
}

__global__ __launch_bounds__(256, 5)
void QKBmm_74062416052397_kernel(const float* __restrict__ q,
                                 const float* __restrict__ k,
                                 float* __restrict__ out) {
    // Half-K (64-col) buffers: A 64x64 (8KB), B 128x64 (16KB) = 24KB total.
    __shared__ __bf16 As[64 * 64];
    __shared__ __bf16 Bs[128 * 64];

    const int t = threadIdx.x;         // 0..255

    // XCD-aware remap (bijective, 16384%8==0): n fastest, then m, then bm.
    const unsigned lin = blockIdx.x;
    const unsigned swz = (lin & (NXCD - 1)) * (16384u / NXCD) + (lin >> 3);
    const int nt_ = swz & 31;          // KV tile index (128 cols, fastest)
    const int mt  = (swz >> 5) & 15;   // Q tile index (64 rows)
    const int bm  = swz >> 9;          // batch*M index
    const int m0  = mt * 64;
    const int n0  = nt_ * 128;

    const float4* __restrict__ Q4 =
        reinterpret_cast<const float4*>(q + ((size_t)bm * QT  + m0) * HD);
    const float4* __restrict__ K4 =
        reinterpret_cast<const float4*>(k + ((size_t)bm * KVT + n0) * HD);

    const int lane = t & 63;
    const int wid  = t >> 6;
    const int wm   = (wid >> 1) * 32;  // wave row offset (2x2 waves, 32x64 each)
    const int wn   = (wid & 1) * 64;   // wave col offset
    const int l31  = lane & 31;        // fragment row/col index (32-wide)
    const int kh   = (lane >> 5) * 8;  // k-half offset within K=16 step

    f32x16 acc[2] = {};                // [ni] -> 32 VGPR

    // Staging per half h (fp32 cols h*64.., f4 cols h*16..):
    //   A: 64 rows x 16 f4 = 1024 f4 -> 4 per thread
    //   B: 128 rows x 16 f4 = 2048 f4 -> 8 per thread
    // f = it*256 + t; row = f>>4; c4 = f&15.
    // LDS elem e = (row*64 + c4*4) ^ ((row&7)<<3)  (XOR swizzle, 16B units).
#pragma unroll
    for (int h = 0; h < 2; ++h) {
        if (h) __syncthreads();        // prior compute done reading the buffer

        // batch 1: A it0-1 + B it0-1 (16 VGPR transient)
        {
            float4 v0, v1, v2, v3;
            int f0 = t,          r0 = f0 >> 4, c0 = f0 & 15;
            int f1 = 256 + t,    r1 = f1 >> 4, c1 = f1 & 15;
            v0 = Q4[r0 * 32 + h * 16 + c0];
            v1 = Q4[r1 * 32 + h * 16 + c1];
            v2 = K4[r0 * 32 + h * 16 + c0];
            v3 = K4[r1 * 32 + h * 16 + c1];
            int e0 = (r0 * 64 + c0 * 4) ^ ((r0 & 7) << 3);
            int e1 = (r1 * 64 + c1 * 4) ^ ((r1 & 7) << 3);
            *reinterpret_cast<bf16x4*>(&As[e0]) =
                bf16x4{ (__bf16)v0.x, (__bf16)v0.y, (__bf16)v0.z, (__bf16)v0.w };
            *reinterpret_cast<bf16x4*>(&As[e1]) =
                bf16x4{ (__bf16)v1.x, (__bf16)v1.y, (__bf16)v1.z, (__bf16)v1.w };
            *reinterpret_cast<bf16x4*>(&Bs[e0]) =
                bf16x4{ (__bf16)v2.x, (__bf16)v2.y, (__bf16)v2.z, (__bf16)v2.w };
            *reinterpret_cast<bf16x4*>(&Bs[e1]) =
                bf16x4{ (__bf16)v3.x, (__bf16)v3.y, (__bf16)v3.z, (__bf16)v3.w };
        }
        // batch 2: A it2-3 + B it2-3
        {
            float4 v0, v1, v2, v3;
            int f0 = 512 + t,    r0 = f0 >> 4, c0 = f0 & 15;
            int f1 = 768 + t,    r1 = f1 >> 4, c1 = f1 & 15;
            v0 = Q4[r0 * 32 + h * 16 + c0];
            v1 = Q4[r1 * 32 + h * 16 + c1];
            v2 = K4[r0 * 32 + h * 16 + c0];
            v3 = K4[r1 * 32 + h * 16 + c1];
            int e0 = (r0 * 64 + c0 * 4) ^ ((r0 & 7) << 3);
            int e1 = (r1 * 64 + c1 * 4) ^ ((r1 & 7) << 3);
            *reinterpret_cast<bf16x4*>(&As[e0]) =
                bf16x4{ (__bf16)v0.x, (__bf16)v0.y, (__bf16)v0.z, (__bf16)v0.w };
            *reinterpret_cast<bf16x4*>(&As[e1]) =
                bf16x4{ (__bf16)v1.x, (__bf16)v1.y, (__bf16)v1.z, (__bf16)v1.w };
            *reinterpret_cast<bf16x4*>(&Bs[e0]) =
                bf16x4{ (__bf16)v2.x, (__bf16)v2.y, (__bf16)v2.z, (__bf16)v2.w };
            *reinterpret_cast<bf16x4*>(&Bs[e1]) =
                bf16x4{ (__bf16)v3.x, (__bf16)v3.y, (__bf16)v3.z, (__bf16)v3.w };
        }
        // batch 3: B it4-7
        {
            float4 v0, v1, v2, v3;
            int f0 = 1024 + t, r0 = f0 >> 4, c0 = f0 & 15;
            int f1 = 1280 + t, r1 = f1 >> 4, c1 = f1 & 15;
            int f2 = 1536 + t, r2 = f2 >> 4, c2 = f2 & 15;
            int f3 = 1792 + t, r3 = f3 >> 4, c3 = f3 & 15;
            v0 = K4[r0 * 32 + h * 16 + c0];
            v1 = K4[r1 * 32 + h * 16 + c1];
            v2 = K4[r2 * 32 + h * 16 + c2];
            v3 = K4[r3 * 32 + h * 16 + c3];
            int e0 = (r0 * 64 + c0 * 4) ^ ((r0 & 7) << 3);
            int e1 = (r1 * 64 + c1 * 4) ^ ((r1 & 7) << 3);
            int e2 = (r2 * 64 + c2 * 4) ^ ((r2 & 7) << 3);
            int e3 = (r3 * 64 + c3 * 4) ^ ((r3 & 7) << 3);
            *reinterpret_cast<bf16x4*>(&Bs[e0]) =
                bf16x4{ (__bf16)v0.x, (__bf16)v0.y, (__bf16)v0.z, (__bf16)v0.w };
            *reinterpret_cast<bf16x4*>(&Bs[e1]) =
                bf16x4{ (__bf16)v1.x, (__bf16)v1.y, (__bf16)v1.z, (__bf16)v1.w };
            *reinterpret_cast<bf16x4*>(&Bs[e2]) =
                bf16x4{ (__bf16)v2.x, (__bf16)v2.y, (__bf16)v2.z, (__bf16)v2.w };
            *reinterpret_cast<bf16x4*>(&Bs[e3]) =
                bf16x4{ (__bf16)v3.x, (__bf16)v3.y, (__bf16)v3.z, (__bf16)v3.w };
        }
        __syncthreads();

        // ---- Compute 4 K-steps (K=16 each) from the staged half.
        //      32x32x16: A row = lane&31, k = (lane>>5)*8 + j; B symmetric.
#pragma unroll
        for (int ks = 0; ks < 4; ++ks) {
            const int kcol = ks * 16 + kh;
            int ra = wm + l31;
            int ea = (ra * 64 + kcol) ^ ((ra & 7) << 3);
            bf16x8 af = *reinterpret_cast<const bf16x8*>(&As[ea]);
#pragma unroll
            for (int ni = 0; ni < 2; ++ni) {
                int rb = wn + ni * 32 + l31;
                int eb = (rb * 64 + kcol) ^ ((rb & 7) << 3);
                bf16x8 bfr = *reinterpret_cast<const bf16x8*>(&Bs[eb]);
                acc[ni] = __builtin_amdgcn_mfma_f32_32x32x16_bf16(
                    af, bfr, acc[ni], 0, 0, 0);
            }
        }
    }

    // ---- Epilogue: 32x32 C/D layout: col = lane&31 (contiguous 128B),
    //      row = (r&3) + 8*(r>>2) + 4*(lane>>5). Each scalar store instr
    //      writes 2 complete 128B lines. Flags: sc1 (L2 bypass, L3 alloc).
    float* __restrict__ Cp = out + (size_t)bm * QT * KVT;
#pragma unroll
    for (int ni = 0; ni < 2; ++ni) {
#pragma unroll
        for (int r = 0; r < 16; ++r) {
            int row = m0 + wm + (r & 3) + 8 * (r >> 2) + 4 * (lane >> 5);
            float* rp = Cp + (size_t)row * KVT + n0 + wn + ni * 32 + l31;
            store_sc1(rp, acc[ni][r]);
        }
    }
}

extern "C" void kernel_launch(void* const* d_in, const int* in_sizes, int n_in,
                              void* d_out, int out_size, void* d_ws, size_t ws_size,
                              hipStream_t stream) {
    const float* q = (const float*)d_in[0];
    const float* k = (const float*)d_in[1];
    float* out = (float*)d_out;

    QKBmm_74062416052397_kernel<<<dim3(16384), dim3(256), 0, stream>>>(q, k, out);
}

// Round 13
// 140.129 us; speedup vs baseline: 1.3185x; 1.3185x over previous
//
#include <hip/hip_runtime.h>

// QKBmm: out[b,m,q,kv] = sum_h q[b,m,q,h] * k[b,m,kv,h]
// B=2, M=16, QT=1024, KVT=4096, H=128. fp32 in/out, bf16 MFMA compute.
// Write-bound: 512 MB out; inputs L3-resident. Floor ~91-94us.
// R6 WIN (4 blk/CU). R8 121.9 (5 blk/CU neutral). R9 FAILED (pipeline).
// R10 FAILED (plain stores). R11 WIN 118.7 (32x32 MFMA, full-line NT).
// R12 FAILED (184.8): sc1 L2-bypass — nt is the right flag. Reverted.
// R13: DRAM page locality — 32x256 tile doubles per-row contiguous write
//     chunk to 1KB (vs 512B at 16KB stride); n-fastest swizzle keeps all 16
//     nt-tiles of the same rows concurrently in flight per XCD. acc stays
//     32 VGPR; LDS 36KB -> 4 blk/CU; rest identical to R11.

#define QT   1024
#define KVT  4096
#define HD   128
#define NXCD 8

using bf16x8 = __attribute__((ext_vector_type(8))) __bf16;
using bf16x4 = __attribute__((ext_vector_type(4))) __bf16;
using f32x16 = __attribute__((ext_vector_type(16))) float;

__global__ __launch_bounds__(256, 4)
void QKBmm_74062416052397_kernel(const float* __restrict__ q,
                                 const float* __restrict__ k,
                                 float* __restrict__ out) {
    // Half-K (64-col) buffers: A 32x64 (4KB), B 256x64 (32KB) = 36KB total.
    __shared__ __bf16 As[32 * 64];
    __shared__ __bf16 Bs[256 * 64];

    const int t = threadIdx.x;         // 0..255

    // XCD-aware remap (bijective, 16384%8==0): n fastest, then m, then bm.
    const unsigned lin = blockIdx.x;
    const unsigned swz = (lin & (NXCD - 1)) * (16384u / NXCD) + (lin >> 3);
    const int nt_ = swz & 15;          // KV tile index (256 cols, fastest)
    const int mt  = (swz >> 4) & 31;   // Q tile index (32 rows)
    const int bm  = swz >> 9;          // batch*M index
    const int m0  = mt * 32;
    const int n0  = nt_ * 256;

    const float4* __restrict__ Q4 =
        reinterpret_cast<const float4*>(q + ((size_t)bm * QT  + m0) * HD);
    const float4* __restrict__ K4 =
        reinterpret_cast<const float4*>(k + ((size_t)bm * KVT + n0) * HD);

    const int lane = t & 63;
    const int wid  = t >> 6;
    const int wn   = wid * 64;         // wave col offset (4 waves x 32x64)
    const int l31  = lane & 31;        // fragment row/col index (32-wide)
    const int kh   = (lane >> 5) * 8;  // k-half offset within K=16 step

    f32x16 acc[2] = {};                // [ni] -> 32 VGPR

    // Staging per half h (fp32 cols h*64.., f4 cols h*16..):
    //   A: 32 rows x 16 f4 =  512 f4 -> 2 per thread
    //   B: 256 rows x 16 f4 = 4096 f4 -> 16 per thread (4 batches of 4)
    // f = it*256 + t; row = f>>4; c4 = f&15.
    // LDS elem e = (row*64 + c4*4) ^ ((row&7)<<3)  (XOR swizzle, 16B units).
#pragma unroll
    for (int h = 0; h < 2; ++h) {
        if (h) __syncthreads();        // prior compute done reading the buffer

        // ---- A: 2 f4/thread ----
        {
            float4 v0, v1;
            int f0 = t,       r0 = f0 >> 4, c0 = f0 & 15;
            int f1 = 256 + t, r1 = f1 >> 4, c1 = f1 & 15;
            v0 = Q4[r0 * 32 + h * 16 + c0];
            v1 = Q4[r1 * 32 + h * 16 + c1];
            int e0 = (r0 * 64 + c0 * 4) ^ ((r0 & 7) << 3);
            int e1 = (r1 * 64 + c1 * 4) ^ ((r1 & 7) << 3);
            *reinterpret_cast<bf16x4*>(&As[e0]) =
                bf16x4{ (__bf16)v0.x, (__bf16)v0.y, (__bf16)v0.z, (__bf16)v0.w };
            *reinterpret_cast<bf16x4*>(&As[e1]) =
                bf16x4{ (__bf16)v1.x, (__bf16)v1.y, (__bf16)v1.z, (__bf16)v1.w };
        }
        // ---- B: 16 f4/thread, 4 batches of 4 (16 VGPR transient) ----
#pragma unroll
        for (int b4 = 0; b4 < 4; ++b4) {
            float4 v[4];
#pragma unroll
            for (int j = 0; j < 4; ++j) {
                int f = (b4 * 4 + j) * 256 + t, row = f >> 4, c4 = f & 15;
                v[j] = K4[row * 32 + h * 16 + c4];
            }
#pragma unroll
            for (int j = 0; j < 4; ++j) {
                int f = (b4 * 4 + j) * 256 + t, row = f >> 4, c4 = f & 15;
                int e = (row * 64 + c4 * 4) ^ ((row & 7) << 3);
                *reinterpret_cast<bf16x4*>(&Bs[e]) =
                    bf16x4{ (__bf16)v[j].x, (__bf16)v[j].y,
                            (__bf16)v[j].z, (__bf16)v[j].w };
            }
        }
        __syncthreads();

        // ---- Compute 4 K-steps (K=16 each) from the staged half.
        //      32x32x16: A row = lane&31, k = (lane>>5)*8 + j; B symmetric.
#pragma unroll
        for (int ks = 0; ks < 4; ++ks) {
            const int kcol = ks * 16 + kh;
            int ra = l31;
            int ea = (ra * 64 + kcol) ^ ((ra & 7) << 3);
            bf16x8 af = *reinterpret_cast<const bf16x8*>(&As[ea]);
#pragma unroll
            for (int ni = 0; ni < 2; ++ni) {
                int rb = wn + ni * 32 + l31;
                int eb = (rb * 64 + kcol) ^ ((rb & 7) << 3);
                bf16x8 bfr = *reinterpret_cast<const bf16x8*>(&Bs[eb]);
                acc[ni] = __builtin_amdgcn_mfma_f32_32x32x16_bf16(
                    af, bfr, acc[ni], 0, 0, 0);
            }
        }
    }

    // ---- Epilogue: 32x32 C/D layout: col = lane&31 (contiguous 128B),
    //      row = (r&3) + 8*(r>>2) + 4*(lane>>5). Each scalar NT dword store
    //      instruction writes 2 complete 128B lines — zero partial lines.
    float* __restrict__ Cp = out + (size_t)bm * QT * KVT;
#pragma unroll
    for (int ni = 0; ni < 2; ++ni) {
#pragma unroll
        for (int r = 0; r < 16; ++r) {
            int row = m0 + (r & 3) + 8 * (r >> 2) + 4 * (lane >> 5);
            float* rp = Cp + (size_t)row * KVT + n0 + wn + ni * 32 + l31;
            __builtin_nontemporal_store(acc[ni][r], rp);
        }
    }
}

extern "C" void kernel_launch(void* const* d_in, const int* in_sizes, int n_in,
                              void* d_out, int out_size, void* d_ws, size_t ws_size,
                              hipStream_t stream) {
    const float* q = (const float*)d_in[0];
    const float* k = (const float*)d_in[1];
    float* out = (float*)d_out;

    QKBmm_74062416052397_kernel<<<dim3(16384), dim3(256), 0, stream>>>(q, k, out);
}

// Round 14
// 117.554 us; speedup vs baseline: 1.5718x; 1.1920x over previous
//
#include <hip/hip_runtime.h>

// QKBmm: out[b,m,q,kv] = sum_h q[b,m,q,h] * k[b,m,kv,h]
// B=2, M=16, QT=1024, KVT=4096, H=128. fp32 in/out, bf16 MFMA compute.
// Write-bound: 512 MB out; inputs L3-resident. Floor ~98-100us (mixed, NT).
// R6 WIN (4 blk/CU). R8 121.9 (5 blk/CU). R9 FAILED (manual pipeline).
// R10 FAILED (plain). R11 WIN 118.7 (32x32 MFMA full-line NT). R12 FAILED
// (sc1). R13 FAILED (32x256: staging ratio +50%).
// R14: staging-LATENCY fix. R11's 4-load batches reused regs -> 3 serialized
//     ~400cy L2 exposures per phase (measured phase 1100cy vs 200cy work).
//     Now: single 12-load batch into distinct regs + h1 loads issued BEFORE
//     compute h0 (ds_write after the post-compute barrier). lb(256,4) for
//     the +48 VGPR transient. Everything else = R11.

#define QT   1024
#define KVT  4096
#define HD   128
#define NXCD 8

using bf16x8 = __attribute__((ext_vector_type(8))) __bf16;
using bf16x4 = __attribute__((ext_vector_type(4))) __bf16;
using f32x16 = __attribute__((ext_vector_type(16))) float;

__global__ __launch_bounds__(256, 4)
void QKBmm_74062416052397_kernel(const float* __restrict__ q,
                                 const float* __restrict__ k,
                                 float* __restrict__ out) {
    // Half-K (64-col) buffers: A 64x64 (8KB), B 128x64 (16KB) = 24KB total.
    __shared__ __bf16 As[64 * 64];
    __shared__ __bf16 Bs[128 * 64];

    const int t = threadIdx.x;         // 0..255

    // XCD-aware remap (bijective, 16384%8==0): n fastest, then m, then bm.
    const unsigned lin = blockIdx.x;
    const unsigned swz = (lin & (NXCD - 1)) * (16384u / NXCD) + (lin >> 3);
    const int nt_ = swz & 31;          // KV tile index (128 cols, fastest)
    const int mt  = (swz >> 5) & 15;   // Q tile index (64 rows)
    const int bm  = swz >> 9;          // batch*M index
    const int m0  = mt * 64;
    const int n0  = nt_ * 128;

    const float4* __restrict__ Q4 =
        reinterpret_cast<const float4*>(q + ((size_t)bm * QT  + m0) * HD);
    const float4* __restrict__ K4 =
        reinterpret_cast<const float4*>(k + ((size_t)bm * KVT + n0) * HD);

    const int lane = t & 63;
    const int wid  = t >> 6;
    const int wm   = (wid >> 1) * 32;  // wave row offset (2x2 waves, 32x64 each)
    const int wn   = (wid & 1) * 64;   // wave col offset
    const int l31  = lane & 31;        // fragment row/col index (32-wide)
    const int kh   = (lane >> 5) * 8;  // k-half offset within K=16 step

    f32x16 acc[2] = {};                // [ni] -> 32 VGPR

    // Staging geometry per half h: A 64 rows x 16 f4 (4/thr), B 128 x 16 f4
    // (8/thr). f = it*256 + t; row = f>>4; c4 = f&15.
    // LDS elem e = (row*64 + c4*4) ^ ((row&7)<<3)  (XOR swizzle, 16B units).

    // ---- Issue h0 loads: single batch, distinct regs (one L2 exposure) ----
    float4 qa[4], kb[8];
#pragma unroll
    for (int it = 0; it < 4; ++it) {
        int f = it * 256 + t, r = f >> 4, c = f & 15;
        qa[it] = Q4[r * 32 + c];
    }
#pragma unroll
    for (int it = 0; it < 8; ++it) {
        int f = it * 256 + t, r = f >> 4, c = f & 15;
        kb[it] = K4[r * 32 + c];
    }

    // ---- ds_write h0 (compiler inserts the single vmcnt wait) ----
#pragma unroll
    for (int it = 0; it < 4; ++it) {
        int f = it * 256 + t, r = f >> 4, c = f & 15;
        int e = (r * 64 + c * 4) ^ ((r & 7) << 3);
        *reinterpret_cast<bf16x4*>(&As[e]) =
            bf16x4{ (__bf16)qa[it].x, (__bf16)qa[it].y,
                    (__bf16)qa[it].z, (__bf16)qa[it].w };
    }
#pragma unroll
    for (int it = 0; it < 8; ++it) {
        int f = it * 256 + t, r = f >> 4, c = f & 15;
        int e = (r * 64 + c * 4) ^ ((r & 7) << 3);
        *reinterpret_cast<bf16x4*>(&Bs[e]) =
            bf16x4{ (__bf16)kb[it].x, (__bf16)kb[it].y,
                    (__bf16)kb[it].z, (__bf16)kb[it].w };
    }

    // ---- Issue h1 loads EARLY (latency hides under compute h0) ----
    float4 qa1[4], kb1[8];
#pragma unroll
    for (int it = 0; it < 4; ++it) {
        int f = it * 256 + t, r = f >> 4, c = f & 15;
        qa1[it] = Q4[r * 32 + 16 + c];
    }
#pragma unroll
    for (int it = 0; it < 8; ++it) {
        int f = it * 256 + t, r = f >> 4, c = f & 15;
        kb1[it] = K4[r * 32 + 16 + c];
    }

    __syncthreads();                   // h0 staged

    // ---- Compute h0 ----
#pragma unroll
    for (int ks = 0; ks < 4; ++ks) {
        const int kcol = ks * 16 + kh;
        int ra = wm + l31;
        int ea = (ra * 64 + kcol) ^ ((ra & 7) << 3);
        bf16x8 af = *reinterpret_cast<const bf16x8*>(&As[ea]);
#pragma unroll
        for (int ni = 0; ni < 2; ++ni) {
            int rb = wn + ni * 32 + l31;
            int eb = (rb * 64 + kcol) ^ ((rb & 7) << 3);
            bf16x8 bfr = *reinterpret_cast<const bf16x8*>(&Bs[eb]);
            acc[ni] = __builtin_amdgcn_mfma_f32_32x32x16_bf16(
                af, bfr, acc[ni], 0, 0, 0);
        }
    }

    __syncthreads();                   // all waves done reading h0

    // ---- ds_write h1 (loads long since landed) ----
#pragma unroll
    for (int it = 0; it < 4; ++it) {
        int f = it * 256 + t, r = f >> 4, c = f & 15;
        int e = (r * 64 + c * 4) ^ ((r & 7) << 3);
        *reinterpret_cast<bf16x4*>(&As[e]) =
            bf16x4{ (__bf16)qa1[it].x, (__bf16)qa1[it].y,
                    (__bf16)qa1[it].z, (__bf16)qa1[it].w };
    }
#pragma unroll
    for (int it = 0; it < 8; ++it) {
        int f = it * 256 + t, r = f >> 4, c = f & 15;
        int e = (r * 64 + c * 4) ^ ((r & 7) << 3);
        *reinterpret_cast<bf16x4*>(&Bs[e]) =
            bf16x4{ (__bf16)kb1[it].x, (__bf16)kb1[it].y,
                    (__bf16)kb1[it].z, (__bf16)kb1[it].w };
    }

    __syncthreads();                   // h1 staged

    // ---- Compute h1 ----
#pragma unroll
    for (int ks = 0; ks < 4; ++ks) {
        const int kcol = ks * 16 + kh;
        int ra = wm + l31;
        int ea = (ra * 64 + kcol) ^ ((ra & 7) << 3);
        bf16x8 af = *reinterpret_cast<const bf16x8*>(&As[ea]);
#pragma unroll
        for (int ni = 0; ni < 2; ++ni) {
            int rb = wn + ni * 32 + l31;
            int eb = (rb * 64 + kcol) ^ ((rb & 7) << 3);
            bf16x8 bfr = *reinterpret_cast<const bf16x8*>(&Bs[eb]);
            acc[ni] = __builtin_amdgcn_mfma_f32_32x32x16_bf16(
                af, bfr, acc[ni], 0, 0, 0);
        }
    }

    // ---- Epilogue (R11 exact): 32x32 C/D: col = lane&31 (contiguous 128B),
    //      row = (r&3) + 8*(r>>2) + 4*(lane>>5). Each scalar NT dword store
    //      instruction writes 2 complete 128B lines.
    float* __restrict__ Cp = out + (size_t)bm * QT * KVT;
#pragma unroll
    for (int ni = 0; ni < 2; ++ni) {
#pragma unroll
        for (int r = 0; r < 16; ++r) {
            int row = m0 + wm + (r & 3) + 8 * (r >> 2) + 4 * (lane >> 5);
            float* rp = Cp + (size_t)row * KVT + n0 + wn + ni * 32 + l31;
            __builtin_nontemporal_store(acc[ni][r], rp);
        }
    }
}

extern "C" void kernel_launch(void* const* d_in, const int* in_sizes, int n_in,
                              void* d_out, int out_size, void* d_ws, size_t ws_size,
                              hipStream_t stream) {
    const float* q = (const float*)d_in[0];
    const float* k = (const float*)d_in[1];
    float* out = (float*)d_out;

    QKBmm_74062416052397_kernel<<<dim3(16384), dim3(256), 0, stream>>>(q, k, out);
}